// Round 2
// baseline (2074.868 us; speedup 1.0000x reference)
//
#include <hip/hip_runtime.h>

typedef unsigned int u32;
typedef unsigned long long u64;
typedef unsigned short u16;

#define NTOT 67108864u      // 8192*8192
#define NB   8388608u       // 2^23 score bins (uniform has 23 random mantissa bits)
#define T0   7400000u       // static candidate threshold; true cutoff ~7.55M (margin ~180 sigma)
#define SEGS 512
#define SEG_CAP 15872u      // expected ~13.9K/seg, +17 sigma margin
#define KSPLIT 4

struct Scalars {
  double sumW;
  double sumW2;
  u64 npruned;
  u64 nflip;
  float stdf;
  float pad;
};

// ---- ws layout (bytes) ----
#define OFF_SUF    0ull
#define OFF_SC     33554440ull
#define OFF_BCNT   33554504ull
#define OFF_PAIRS  33556552ull                 // 512*15872*8 = 65,011,712
#define OFF_CAND   98568264ull                 // 8,126,464 * 4
#define OFF_XBF    131074128ull                // 256*8192*2, 16B aligned
#define OFF_SCHUNK 135268432ull
#define OFF_COFF   135301200ull
// total ~135.3 MB

// JAX Threefry-2x32, 20 rounds — verified vs known-answer vector
// tf(0,0,0,0) = (0x6b200159, 0x99ba4efe).
__host__ __device__ inline void tf2x32(u32 k0, u32 k1, u32 x0, u32 x1, u32& y0, u32& y1) {
  u32 ks2 = k0 ^ k1 ^ 0x1BD11BDAu;
  x0 += k0; x1 += k1;
#define TFR(r) { x0 += x1; x1 = (x1 << (r)) | (x1 >> (32 - (r))); x1 ^= x0; }
  TFR(13) TFR(15) TFR(26) TFR(6)  x0 += k1;  x1 += ks2 + 1u;
  TFR(17) TFR(29) TFR(16) TFR(24) x0 += ks2; x1 += k0 + 2u;
  TFR(13) TFR(15) TFR(26) TFR(6)  x0 += k0;  x1 += k1 + 3u;
  TFR(17) TFR(29) TFR(16) TFR(24) x0 += k1;  x1 += ks2 + 4u;
  TFR(13) TFR(15) TFR(26) TFR(6)  x0 += ks2; x1 += k0 + 5u;
#undef TFR
  y0 = x0; y1 = x1;
}

// Partitionable-mode random bits for element i (i < 2^32): counter (hi=0, lo=i),
// bits = y0 ^ y1  (jax._src.prng._threefry_random_bits_partitionable, 32-bit path)
__device__ inline u32 jax_bits32(u32 k0, u32 k1, u32 i) {
  u32 y0, y1; tf2x32(k0, k1, 0u, i, y0, y1);
  return y0 ^ y1;
}

__device__ inline u16 f2bf(float f) {
  union { float f; u32 u; } c; c.f = f;
  u32 r = ((c.u >> 16) & 1u) + 0x7FFFu;   // RNE
  return (u16)((c.u + r) >> 16);
}

// XLA ErfInv (f32, Giles)
__device__ inline float erfinv32(float x) {
  float w = -log1pf(-x * x);
  float p;
  if (w < 5.0f) {
    w -= 2.5f;
    p = 2.81022636e-08f;
    p = fmaf(p, w, 3.43273939e-07f);
    p = fmaf(p, w, -3.5233877e-06f);
    p = fmaf(p, w, -4.39150654e-06f);
    p = fmaf(p, w, 0.00021858087f);
    p = fmaf(p, w, -0.00125372503f);
    p = fmaf(p, w, -0.00417768164f);
    p = fmaf(p, w, 0.246640727f);
    p = fmaf(p, w, 1.50140941f);
  } else {
    w = sqrtf(w) - 3.0f;
    p = -0.000200214257f;
    p = fmaf(p, w, 0.000100950558f);
    p = fmaf(p, w, 0.00134934322f);
    p = fmaf(p, w, -0.00367342844f);
    p = fmaf(p, w, 0.00573950773f);
    p = fmaf(p, w, -0.0076224613f);
    p = fmaf(p, w, 0.00943887047f);
    p = fmaf(p, w, 1.00167406f);
    p = fmaf(p, w, 2.83297682f);
  }
  return p * x;
}

// Pass 1: stream W once: prune test (W==0 == mask), double sums for std,
// per-element partitionable threefry score, append (score_bin, idx) pairs with
// bin >= T0 into per-block segments.
__global__ __launch_bounds__(256) void k_pass1(const float* __restrict__ W, Scalars* sc,
                                               u32* blockCnt, u64* pairs, u32 uk0, u32 uk1) {
  __shared__ u32 lcnt, lwr;
  if (threadIdx.x == 0) { lcnt = 0; lwr = 0; }
  __syncthreads();
  u32 gid = blockIdx.x * blockDim.x + threadIdx.x;
  u32 stride = gridDim.x * blockDim.x;  // 131072
  u32 lane = threadIdx.x & 63;
  u64 lt = (lane == 0) ? 0ull : (~0ull >> (64 - lane));
  u64 segBase = (u64)blockIdx.x * SEG_CAP;
  double s = 0.0, s2 = 0.0; u32 cnt = 0;
  for (u32 l = gid; l < NTOT; l += stride) {
    u32 bits = jax_bits32(uk0, uk1, l);
    float w = W[l];
    s  += (double)w;
    s2 += (double)w * w;
    bool p = (w == 0.0f);
    cnt += p ? 1u : 0u;
    u32 ub = bits >> 9;
    bool q = p && (ub >= T0);
    u64 m = __ballot(q);
    u32 tot = (u32)__popcll(m);
    if (tot) {
      u32 base = 0;
      if (lane == 0) base = atomicAdd(&lcnt, tot);
      base = __shfl((int)base, 0);
      if (base + tot <= SEG_CAP) {
        if (lane == 0) atomicMax(&lwr, base + tot);
        if (q) pairs[segBase + base + (u32)__popcll(m & lt)] = ((u64)ub << 32) | l;
      }
    }
  }
  for (int o = 32; o > 0; o >>= 1) {
    s += __shfl_down(s, o); s2 += __shfl_down(s2, o); cnt += __shfl_down(cnt, o);
  }
  if (lane == 0) {
    atomicAdd(&sc->sumW, s);
    atomicAdd(&sc->sumW2, s2);
    atomicAdd(&sc->npruned, (u64)cnt);
  }
  __syncthreads();
  if (threadIdx.x == 0) blockCnt[blockIdx.x] = lwr;
}

// Pass 2: n_flip = max(1, trunc(0.1 * n_pruned)) in double (matches Python int(PHI*n)); std.
__global__ void k_pass2(Scalars* sc) {
  double nk = (double)NTOT - (double)sc->npruned;
  double mean = sc->sumW / nk;
  double var = (sc->sumW2 - 2.0 * mean * sc->sumW + nk * mean * mean) / (nk - 1.0);
  sc->stdf = (float)sqrt(var);
  u64 nfi = (u64)(0.1 * (double)sc->npruned);
  if (nfi < 1) nfi = 1;
  sc->nflip = nfi;
}

// Pass 3: histogram of candidate score bins into SUF[]
__global__ __launch_bounds__(256) void k_hist(const u64* __restrict__ pairs,
                                              const u32* __restrict__ blockCnt, u32* SUF) {
  u32 seg = blockIdx.x;
  u32 n = blockCnt[seg];
  const u64* p = pairs + (u64)seg * SEG_CAP;
  for (u32 i = threadIdx.x; i < n; i += blockDim.x)
    atomicAdd(&SUF[(u32)(p[i] >> 32)], 1u);
}

// Suffix-exclusive scan of SUF (strictly-greater counts = global rank base per bin)
__global__ __launch_bounds__(256) void k_scan_a(const u32* __restrict__ SUF, u32* scanChunk) {
  __shared__ u32 red[256];
  u32 base = blockIdx.x * 1024 + threadIdx.x * 4;
  red[threadIdx.x] = SUF[base] + SUF[base + 1] + SUF[base + 2] + SUF[base + 3];
  __syncthreads();
  for (int o = 128; o > 0; o >>= 1) {
    if ((int)threadIdx.x < o) red[threadIdx.x] += red[threadIdx.x + o];
    __syncthreads();
  }
  if (threadIdx.x == 0) scanChunk[blockIdx.x] = red[0];
}

__global__ __launch_bounds__(256) void k_scan_b(const u32* __restrict__ scanChunk, u32* chunkOff) {
  __shared__ u32 part[256]; __shared__ u32 off[256];
  u32 t = threadIdx.x;
  u32 sm = 0;
  for (int j = 0; j < 32; j++) sm += scanChunk[t * 32 + j];
  part[t] = sm; __syncthreads();
  if (t == 0) { u32 a = 0; for (int i = 255; i >= 0; i--) { off[i] = a; a += part[i]; } }
  __syncthreads();
  u32 a = off[t];
  for (int j = 31; j >= 0; j--) { u32 c = t * 32 + j; u32 tmp = scanChunk[c]; chunkOff[c] = a; a += tmp; }
}

__global__ __launch_bounds__(256) void k_scan_c(u32* SUF, const u32* __restrict__ chunkOff) {
  __shared__ u32 part[256]; __shared__ u32 off[256];
  u32 c = blockIdx.x, t = threadIdx.x;
  u32 base = c * 1024 + t * 4;
  u32 v0 = SUF[base], v1 = SUF[base + 1], v2 = SUF[base + 2], v3 = SUF[base + 3];
  part[t] = v0 + v1 + v2 + v3; __syncthreads();
  if (t == 0) { u32 a = 0; for (int i = 255; i >= 0; i--) { off[i] = a; a += part[i]; } }
  __syncthreads();
  u32 a = chunkOff[c] + off[t];
  SUF[base + 3] = a; a += v3;
  SUF[base + 2] = a; a += v2;
  SUF[base + 1] = a; a += v1;
  SUF[base + 0] = a;
}

// Pass 6: cursor-fill candidate indices by bin (SUF[ub] doubles as cursor;
// afterwards SUF[s] = count >= s, so segment(s) = [SUF[s+1], SUF[s]) )
__global__ __launch_bounds__(256) void k_fill(const u64* __restrict__ pairs,
                                              const u32* __restrict__ blockCnt,
                                              u32* SUF, u32* cand) {
  u32 seg = blockIdx.x;
  u32 n = blockCnt[seg];
  const u64* p = pairs + (u64)seg * SEG_CAP;
  for (u32 i = threadIdx.x; i < n; i += blockDim.x) {
    u64 pr = p[i];
    u32 pos = atomicAdd(&SUF[(u32)(pr >> 32)], 1u);
    cand[pos] = (u32)pr;
  }
}

// Pass 7: per-bin stable ordinal (ascending index = stable descending top_k),
// rank = rank_base(bin) + ordinal; if rank < n_flip write val(rank) into W.
__global__ __launch_bounds__(256) void k_scatter(float* __restrict__ W,
                                                 const u32* __restrict__ SUF,
                                                 const u32* __restrict__ cand,
                                                 const Scalars* __restrict__ sc,
                                                 u32 vk0, u32 vk1) {
  u32 s = blockIdx.x * blockDim.x + threadIdx.x;
  if (s < T0 || s >= NB) return;
  u32 segStart = SUF[s + 1];
  u32 segEnd = SUF[s];
  if (segEnd <= segStart) return;
  u64 nflip = sc->nflip;
  if ((u64)segStart >= nflip) return;
  float stdf = sc->stdf;
  for (u32 p = segStart; p < segEnd; p++) {
    u32 idx = cand[p];
    u32 ord = 0;
    for (u32 q = segStart; q < segEnd; q++) ord += (cand[q] < idx) ? 1u : 0u;
    u64 rank = (u64)segStart + ord;
    if (rank >= nflip) continue;
    // partitionable normal: bits[r] = y0^y1 @ counter (0, r) with key kv
    u32 bits = jax_bits32(vk0, vk1, (u32)rank);
    union { u32 u; float f; } cv; cv.u = 0x3F800000u | (bits >> 9);
    float f = cv.f - 1.0f;                 // uniform [0,1)
    const float lo = -0.99999994f;         // nextafter(-1,0); (1 - lo) rounds to 2.0f
    float u2 = fmaxf(lo, f * 2.0f + lo);   // uniform [lo, 1)
    float nrm = 1.41421354f * erfinv32(u2);
    W[idx] = (nrm * stdf) * 0.1f;
  }
}

// x fp32 -> bf16 once (halves GEMM x traffic)
__global__ __launch_bounds__(256) void k_xconv(const float* __restrict__ x, u16* __restrict__ xbf) {
  u32 i = blockIdx.x * blockDim.x + threadIdx.x;  // one float4, 524288 total
  float4 v = ((const float4*)x)[i];
  ushort4 o; o.x = f2bf(v.x); o.y = f2bf(v.y); o.z = f2bf(v.z); o.w = f2bf(v.w);
  ((ushort4*)xbf)[i] = o;
}

// GEMM: out[m][n] = sum_k x[m][k] * W[n][k]. M=256 full per block, N tile 64, split-K=4.
typedef __bf16 bf16x8 __attribute__((ext_vector_type(8)));
typedef float f32x4 __attribute__((ext_vector_type(4)));

__global__ __launch_bounds__(256, 2) void k_gemm(const u16* __restrict__ xbf,
                                                 const float* __restrict__ W,
                                                 float* __restrict__ out) {
  __shared__ u16 xs[256 * 72];   // 256 rows x 64 k, pad to 72
  __shared__ u16 wsm[64 * 72];
  u32 tid = threadIdx.x;
  u32 lane = tid & 63, wv = tid >> 6;
  u32 nt0 = blockIdx.x * 64;
  u32 kbase = blockIdx.y * (8192 / KSPLIT);  // 2048 per split
  f32x4 acc[4][4];
#pragma unroll
  for (int i = 0; i < 4; i++)
#pragma unroll
    for (int j = 0; j < 4; j++) acc[i][j] = (f32x4){0.f, 0.f, 0.f, 0.f};

  for (u32 kb = kbase; kb < kbase + 2048u; kb += 64u) {
#pragma unroll
    for (int r8 = 0; r8 < 8; r8++) {             // stage x tile (bf16, 16B loads)
      u32 row = r8 * 32 + (tid >> 3);
      u32 kseg = (tid & 7) * 8;
      uint4 v = *(const uint4*)(xbf + (u64)row * 8192 + kb + kseg);
      *(uint4*)&xs[row * 72 + kseg] = v;
    }
#pragma unroll
    for (int r = 0; r < 4; r++) {                // stage W tile (fp32 -> bf16 inline)
      u32 f4 = r * 256 + tid;
      u32 row = f4 >> 4;
      u32 kc = (f4 & 15) * 4;
      float4 v = *(const float4*)(W + (u64)(nt0 + row) * 8192 + kb + kc);
      ushort4 o; o.x = f2bf(v.x); o.y = f2bf(v.y); o.z = f2bf(v.z); o.w = f2bf(v.w);
      *(ushort4*)&wsm[row * 72 + kc] = o;
    }
    __syncthreads();
#pragma unroll
    for (int ks = 0; ks < 2; ks++) {
      bf16x8 a[4], b[4];
      u32 koff = ks * 32 + (lane >> 4) * 8;      // A/B frag: idx=lane&15, k=quad*8+j
      u32 rsel = lane & 15;
#pragma unroll
      for (int mt = 0; mt < 4; mt++) a[mt] = *(bf16x8*)&xs[(wv * 64 + mt * 16 + rsel) * 72 + koff];
#pragma unroll
      for (int nt = 0; nt < 4; nt++) b[nt] = *(bf16x8*)&wsm[(nt * 16 + rsel) * 72 + koff];
#pragma unroll
      for (int mt = 0; mt < 4; mt++)
#pragma unroll
        for (int nt = 0; nt < 4; nt++)
          acc[mt][nt] = __builtin_amdgcn_mfma_f32_16x16x32_bf16(a[mt], b[nt], acc[mt][nt], 0, 0, 0);
    }
    __syncthreads();
  }
  // epilogue: D row (M) = quad*4+reg, D col (N) = lane&15 (m89-verified layout)
  u32 quad = lane >> 4, col = lane & 15;
#pragma unroll
  for (int mt = 0; mt < 4; mt++)
#pragma unroll
    for (int nt = 0; nt < 4; nt++) {
      u32 n = nt0 + nt * 16 + col;
#pragma unroll
      for (int rg = 0; rg < 4; rg++) {
        u32 m = wv * 64 + mt * 16 + quad * 4 + rg;
        atomicAdd(&out[(u64)m * 8192 + n], acc[mt][nt][rg]);
      }
    }
}

extern "C" void kernel_launch(void* const* d_in, const int* in_sizes, int n_in,
                              void* d_out, int out_size, void* d_ws, size_t ws_size,
                              hipStream_t stream) {
  const float* x; float* W;
  if (in_sizes[0] == 2097152) { x = (const float*)d_in[0]; W = (float*)d_in[1]; }
  else                        { x = (const float*)d_in[1]; W = (float*)d_in[0]; }
  float* out = (float*)d_out;
  char* ws = (char*)d_ws;

  u32* SUF        = (u32*)(ws + OFF_SUF);
  Scalars* sc     = (Scalars*)(ws + OFF_SC);
  u32* blockCnt   = (u32*)(ws + OFF_BCNT);
  u64* pairs      = (u64*)(ws + OFF_PAIRS);
  u32* cand       = (u32*)(ws + OFF_CAND);
  u16* xbf        = (u16*)(ws + OFF_XBF);
  u32* scanChunk  = (u32*)(ws + OFF_SCHUNK);
  u32* chunkOff   = (u32*)(ws + OFF_COFF);

  // PARTITIONABLE split of key(42) (jax_threefry_partitionable=True default):
  // key[i] = (y0, y1) of threefry(k=(0,42), counter=(hi=0, lo=i))
  u32 a0, a1, b0, b1;
  tf2x32(0u, 42u, 0u, 0u, a0, a1);   // ks = (a0, a1)  -> uniform scores
  tf2x32(0u, 42u, 0u, 1u, b0, b1);   // kv = (b0, b1)  -> normal vals

  hipMemsetAsync(SUF, 0, (size_t)(NB + 2) * 4, stream);
  hipMemsetAsync(sc, 0, sizeof(Scalars), stream);
  hipMemsetAsync(out, 0, (size_t)out_size * 4, stream);

  k_xconv<<<2048, 256, 0, stream>>>(x, xbf);
  k_pass1<<<SEGS, 256, 0, stream>>>(W, sc, blockCnt, pairs, a0, a1);
  k_pass2<<<1, 1, 0, stream>>>(sc);
  k_hist<<<SEGS, 256, 0, stream>>>(pairs, blockCnt, SUF);
  k_scan_a<<<8192, 256, 0, stream>>>(SUF, scanChunk);
  k_scan_b<<<1, 256, 0, stream>>>(scanChunk, chunkOff);
  k_scan_c<<<8192, 256, 0, stream>>>(SUF, chunkOff);
  k_fill<<<SEGS, 256, 0, stream>>>(pairs, blockCnt, SUF, cand);
  k_scatter<<<NB / 256, 256, 0, stream>>>(W, SUF, cand, sc, b0, b1);
  dim3 g(128, KSPLIT);
  k_gemm<<<g, 256, 0, stream>>>(xbf, W, out);
}

// Round 3
// 1166.070 us; speedup vs baseline: 1.7794x; 1.7794x over previous
//
#include <hip/hip_runtime.h>

typedef unsigned int u32;
typedef unsigned long long u64;
typedef unsigned short u16;
typedef unsigned char u8;

#define NTOT 67108864u      // 8192*8192
#define NB   8388608u       // 2^23 score bins
#define T0   7400000u       // candidate threshold; true cutoff ~7.5497M
#define C0   115625u        // T0 >> 6 (exact: 115625*64 == 7,400,000)
#define NBUCK 15447u        // coarse buckets: [C0, 1<<17)
#define NBUCKP 16384u       // padded for scan
#define CAP  704u           // mean 461, sigma 21.5 -> +11.3 sigma
#define KSPLIT 4

struct Scalars {
  double sumW;
  double sumW2;
  u64 npruned;
  u64 nflip;
  float stdf;
  float pad;
};

// ---- ws layout (bytes) ----
#define OFF_CNT   0ull               // 16384 * 4 = 64 KB
#define OFF_RB    65536ull           // 16384 * 4 = 64 KB
#define OFF_SC    131072ull          // 64 B
#define OFF_XBF   131200ull          // 256*8192*2 = 4,194,304
#define OFF_PAIRS 4325504ull         // 15447 * 704 * 4 = 43,498,752
// total ~47.8 MB

// JAX Threefry-2x32, 20 rounds — verified vs known-answer vector
__host__ __device__ inline void tf2x32(u32 k0, u32 k1, u32 x0, u32 x1, u32& y0, u32& y1) {
  u32 ks2 = k0 ^ k1 ^ 0x1BD11BDAu;
  x0 += k0; x1 += k1;
#define TFR(r) { x0 += x1; x1 = (x1 << (r)) | (x1 >> (32 - (r))); x1 ^= x0; }
  TFR(13) TFR(15) TFR(26) TFR(6)  x0 += k1;  x1 += ks2 + 1u;
  TFR(17) TFR(29) TFR(16) TFR(24) x0 += ks2; x1 += k0 + 2u;
  TFR(13) TFR(15) TFR(26) TFR(6)  x0 += k0;  x1 += k1 + 3u;
  TFR(17) TFR(29) TFR(16) TFR(24) x0 += k1;  x1 += ks2 + 4u;
  TFR(13) TFR(15) TFR(26) TFR(6)  x0 += ks2; x1 += k0 + 5u;
#undef TFR
  y0 = x0; y1 = x1;
}

// Partitionable-mode bits for element i: counter (0, i), bits = y0 ^ y1
__device__ inline u32 jax_bits32(u32 k0, u32 k1, u32 i) {
  u32 y0, y1; tf2x32(k0, k1, 0u, i, y0, y1);
  return y0 ^ y1;
}

__device__ inline u16 f2bf(float f) {
  union { float f; u32 u; } c; c.f = f;
  u32 r = ((c.u >> 16) & 1u) + 0x7FFFu;   // RNE
  return (u16)((c.u + r) >> 16);
}

// XLA ErfInv (f32, Giles)
__device__ inline float erfinv32(float x) {
  float w = -log1pf(-x * x);
  float p;
  if (w < 5.0f) {
    w -= 2.5f;
    p = 2.81022636e-08f;
    p = fmaf(p, w, 3.43273939e-07f);
    p = fmaf(p, w, -3.5233877e-06f);
    p = fmaf(p, w, -4.39150654e-06f);
    p = fmaf(p, w, 0.00021858087f);
    p = fmaf(p, w, -0.00125372503f);
    p = fmaf(p, w, -0.00417768164f);
    p = fmaf(p, w, 0.246640727f);
    p = fmaf(p, w, 1.50140941f);
  } else {
    w = sqrtf(w) - 3.0f;
    p = -0.000200214257f;
    p = fmaf(p, w, 0.000100950558f);
    p = fmaf(p, w, 0.00134934322f);
    p = fmaf(p, w, -0.00367342844f);
    p = fmaf(p, w, 0.00573950773f);
    p = fmaf(p, w, -0.0076224613f);
    p = fmaf(p, w, 0.00943887047f);
    p = fmaf(p, w, 1.00167406f);
    p = fmaf(p, w, 2.83297682f);
  }
  return p * x;
}

// Pass 1: stream W once: prune test, f64 sums for std, per-element threefry
// score, scatter candidate (fine<<26|idx) into coarse bucket (temporal-locality
// cursor scatter: consecutive positions are claimed back-to-back -> lines fill
// while L2-resident, single writeback).
__global__ __launch_bounds__(256) void k_pass1(const float* __restrict__ W, Scalars* sc,
                                               u32* cnt, u32* pairs, u32 uk0, u32 uk1) {
  u32 gid = blockIdx.x * blockDim.x + threadIdx.x;
  u32 stride = gridDim.x * blockDim.x;
  u32 lane = threadIdx.x & 63;
  double s = 0.0, s2 = 0.0; u32 c = 0;
  for (u32 l = gid; l < NTOT; l += stride) {
    float w = W[l];
    u32 bits = jax_bits32(uk0, uk1, l);
    s  += (double)w;
    s2 += (double)w * w;
    bool p = (w == 0.0f);
    c += p ? 1u : 0u;
    u32 ub = bits >> 9;
    if (p && ub >= T0) {
      u32 cb = (ub >> 6) - C0;
      u32 pos = atomicAdd(&cnt[cb], 1u);
      if (pos < CAP) pairs[(u64)cb * CAP + pos] = ((ub & 63u) << 26) | l;
    }
  }
  for (int o = 32; o > 0; o >>= 1) {
    s += __shfl_down(s, o); s2 += __shfl_down(s2, o); c += __shfl_down(c, o);
  }
  if (lane == 0) {
    atomicAdd(&sc->sumW, s);
    atomicAdd(&sc->sumW2, s2);
    atomicAdd(&sc->npruned, (u64)c);
  }
}

// Pass 2: n_flip = max(1, trunc(0.1 * n_pruned)); unbiased std.
__global__ void k_pass2(Scalars* sc) {
  double nk = (double)NTOT - (double)sc->npruned;
  double mean = sc->sumW / nk;
  double var = (sc->sumW2 - 2.0 * mean * sc->sumW + nk * mean * mean) / (nk - 1.0);
  sc->stdf = (float)sqrt(var);
  u64 nfi = (u64)(0.1 * (double)sc->npruned);
  if (nfi < 1) nfi = 1;
  sc->nflip = nfi;
}

// Suffix-exclusive scan of bucket counts: rb[b] = sum of clamped counts in
// buckets with HIGHER index (= higher score = better rank). One block.
__global__ __launch_bounds__(256) void k_bscan(const u32* __restrict__ cnt, u32* rb) {
  __shared__ u32 part[256];
  __shared__ u32 off[256];
  u32 t = threadIdx.x;
  u32 base = t * 64;
  u32 s = 0;
  for (int j = 0; j < 64; j++) { u32 v = cnt[base + j]; s += (v > CAP ? CAP : v); }
  part[t] = s;
  __syncthreads();
  if (t == 0) { u32 a = 0; for (int i = 255; i >= 0; i--) { off[i] = a; a += part[i]; } }
  __syncthreads();
  u32 a = off[t];
  for (int j = 63; j >= 0; j--) {
    u32 v = cnt[base + j]; v = (v > CAP ? CAP : v);
    rb[base + j] = a; a += v;
  }
}

// Per-bucket rank resolution: LDS counting-sort by fine bin (desc) with stable
// ascending-idx tie-break; rank = rb[bucket] + position; write flip val to W.
__global__ __launch_bounds__(256) void k_rank(float* __restrict__ W,
                                              const u32* __restrict__ cnt,
                                              const u32* __restrict__ rb,
                                              const u32* __restrict__ pairs,
                                              const Scalars* __restrict__ sc,
                                              u32 vk0, u32 vk1) {
  u32 b = blockIdx.x;
  u32 n = cnt[b]; if (n > CAP) n = CAP;
  if (n == 0) return;
  u64 nflip = sc->nflip;
  u32 base = rb[b];
  if ((u64)base >= nflip) return;      // whole bucket ranks below cutoff
  __shared__ u32 sIdx[CAP];
  __shared__ u8  sFine[CAP];
  __shared__ u32 pIdx[CAP];
  __shared__ u32 hist[64];
  __shared__ u32 gbase[64];
  __shared__ u32 cur[64];
  if (threadIdx.x < 64) hist[threadIdx.x] = 0;
  __syncthreads();
  const u32* slice = pairs + (u64)b * CAP;
  for (u32 i = threadIdx.x; i < n; i += 256) {
    u32 e = slice[i];
    u32 fi = e >> 26;
    sIdx[i] = e & 0x03FFFFFFu;
    sFine[i] = (u8)fi;
    atomicAdd(&hist[fi], 1u);
  }
  __syncthreads();
  if (threadIdx.x == 0) {
    u32 a = 0;
    for (int f = 63; f >= 0; f--) { gbase[f] = a; cur[f] = a; a += hist[f]; }
  }
  __syncthreads();
  for (u32 i = threadIdx.x; i < n; i += 256) {
    u32 p = atomicAdd(&cur[sFine[i]], 1u);
    pIdx[p] = sIdx[i];
  }
  __syncthreads();
  float stdf = sc->stdf;
  for (u32 i = threadIdx.x; i < n; i += 256) {
    u32 f = sFine[i];
    u32 g0 = gbase[f], g1 = g0 + hist[f];
    u32 v = sIdx[i];
    u32 ord = 0;
    for (u32 q = g0; q < g1; q++) ord += (pIdx[q] < v) ? 1u : 0u;
    u64 rank = (u64)base + gbase[f] + ord;
    if (rank >= nflip) continue;
    u32 bits = jax_bits32(vk0, vk1, (u32)rank);
    union { u32 u; float fl; } cv; cv.u = 0x3F800000u | (bits >> 9);
    float fu = cv.fl - 1.0f;               // uniform [0,1)
    const float lo = -0.99999994f;         // nextafter(-1,0); (1-lo) rounds to 2.0f
    float u2 = fmaxf(lo, fu * 2.0f + lo);  // uniform [lo, 1)
    float nrm = 1.41421354f * erfinv32(u2);
    W[v] = (nrm * stdf) * 0.1f;
  }
}

// x fp32 -> bf16 once
__global__ __launch_bounds__(256) void k_xconv(const float* __restrict__ x, u16* __restrict__ xbf) {
  u32 i = blockIdx.x * blockDim.x + threadIdx.x;  // one float4, 524288 total
  float4 v = ((const float4*)x)[i];
  ushort4 o; o.x = f2bf(v.x); o.y = f2bf(v.y); o.z = f2bf(v.z); o.w = f2bf(v.w);
  ((ushort4*)xbf)[i] = o;
}

// GEMM: out[m][n] = sum_k x[m][k] * W[n][k]. M=256 full per block, N tile 64, split-K=4.
typedef __bf16 bf16x8 __attribute__((ext_vector_type(8)));
typedef float f32x4 __attribute__((ext_vector_type(4)));

__global__ __launch_bounds__(256, 2) void k_gemm(const u16* __restrict__ xbf,
                                                 const float* __restrict__ W,
                                                 float* __restrict__ out) {
  __shared__ u16 xs[256 * 72];   // 256 rows x 64 k, pad to 72
  __shared__ u16 wsm[64 * 72];
  u32 tid = threadIdx.x;
  u32 lane = tid & 63, wv = tid >> 6;
  u32 nt0 = blockIdx.x * 64;
  u32 kbase = blockIdx.y * (8192 / KSPLIT);  // 2048 per split
  f32x4 acc[4][4];
#pragma unroll
  for (int i = 0; i < 4; i++)
#pragma unroll
    for (int j = 0; j < 4; j++) acc[i][j] = (f32x4){0.f, 0.f, 0.f, 0.f};

  for (u32 kb = kbase; kb < kbase + 2048u; kb += 64u) {
#pragma unroll
    for (int r8 = 0; r8 < 8; r8++) {             // stage x tile (bf16, 16B loads)
      u32 row = r8 * 32 + (tid >> 3);
      u32 kseg = (tid & 7) * 8;
      uint4 v = *(const uint4*)(xbf + (u64)row * 8192 + kb + kseg);
      *(uint4*)&xs[row * 72 + kseg] = v;
    }
#pragma unroll
    for (int r = 0; r < 4; r++) {                // stage W tile (fp32 -> bf16 inline)
      u32 f4 = r * 256 + tid;
      u32 row = f4 >> 4;
      u32 kc = (f4 & 15) * 4;
      float4 v = *(const float4*)(W + (u64)(nt0 + row) * 8192 + kb + kc);
      ushort4 o; o.x = f2bf(v.x); o.y = f2bf(v.y); o.z = f2bf(v.z); o.w = f2bf(v.w);
      *(ushort4*)&wsm[row * 72 + kc] = o;
    }
    __syncthreads();
#pragma unroll
    for (int ks = 0; ks < 2; ks++) {
      bf16x8 a[4], b[4];
      u32 koff = ks * 32 + (lane >> 4) * 8;      // A/B frag: idx=lane&15, k=quad*8+j
      u32 rsel = lane & 15;
#pragma unroll
      for (int mt = 0; mt < 4; mt++) a[mt] = *(bf16x8*)&xs[(wv * 64 + mt * 16 + rsel) * 72 + koff];
#pragma unroll
      for (int nt = 0; nt < 4; nt++) b[nt] = *(bf16x8*)&wsm[(nt * 16 + rsel) * 72 + koff];
#pragma unroll
      for (int mt = 0; mt < 4; mt++)
#pragma unroll
        for (int nt = 0; nt < 4; nt++)
          acc[mt][nt] = __builtin_amdgcn_mfma_f32_16x16x32_bf16(a[mt], b[nt], acc[mt][nt], 0, 0, 0);
    }
    __syncthreads();
  }
  // epilogue: D row (M) = quad*4+reg, D col (N) = lane&15
  u32 quad = lane >> 4, col = lane & 15;
#pragma unroll
  for (int mt = 0; mt < 4; mt++)
#pragma unroll
    for (int nt = 0; nt < 4; nt++) {
      u32 n = nt0 + nt * 16 + col;
#pragma unroll
      for (int rg = 0; rg < 4; rg++) {
        u32 m = wv * 64 + mt * 16 + quad * 4 + rg;
        atomicAdd(&out[(u64)m * 8192 + n], acc[mt][nt][rg]);
      }
    }
}

extern "C" void kernel_launch(void* const* d_in, const int* in_sizes, int n_in,
                              void* d_out, int out_size, void* d_ws, size_t ws_size,
                              hipStream_t stream) {
  const float* x; float* W;
  if (in_sizes[0] == 2097152) { x = (const float*)d_in[0]; W = (float*)d_in[1]; }
  else                        { x = (const float*)d_in[1]; W = (float*)d_in[0]; }
  float* out = (float*)d_out;
  char* ws = (char*)d_ws;

  u32* cnt    = (u32*)(ws + OFF_CNT);
  u32* rb     = (u32*)(ws + OFF_RB);
  Scalars* sc = (Scalars*)(ws + OFF_SC);
  u16* xbf    = (u16*)(ws + OFF_XBF);
  u32* pairs  = (u32*)(ws + OFF_PAIRS);

  // PARTITIONABLE split of key(42): key[i] = threefry(k=(0,42), counter=(0,i))
  u32 a0, a1, b0, b1;
  tf2x32(0u, 42u, 0u, 0u, a0, a1);   // ks -> uniform scores
  tf2x32(0u, 42u, 0u, 1u, b0, b1);   // kv -> normal vals

  hipMemsetAsync(cnt, 0, (size_t)NBUCKP * 4, stream);
  hipMemsetAsync(sc, 0, sizeof(Scalars), stream);
  hipMemsetAsync(out, 0, (size_t)out_size * 4, stream);

  k_xconv<<<2048, 256, 0, stream>>>(x, xbf);
  k_pass1<<<2048, 256, 0, stream>>>(W, sc, cnt, pairs, a0, a1);
  k_pass2<<<1, 1, 0, stream>>>(sc);
  k_bscan<<<1, 256, 0, stream>>>(cnt, rb);
  k_rank<<<NBUCK, 256, 0, stream>>>(W, cnt, rb, pairs, sc, b0, b1);
  dim3 g(128, KSPLIT);
  k_gemm<<<g, 256, 0, stream>>>(xbf, W, out);
}

// Round 4
// 1153.291 us; speedup vs baseline: 1.7991x; 1.0111x over previous
//
#include <hip/hip_runtime.h>

typedef unsigned int u32;
typedef unsigned long long u64;
typedef unsigned short u16;

#define NTOT   67108864u    // 8192*8192 = 2^26
#define T0P    7399424u     // candidate threshold (= 2^23 - 966*1024); true cutoff ~7.5497M
#define PBASE  7226u        // T0P >> 10
#define NSUP   966u         // supers of 1024 fine bins each
#define SEGN   2048u        // pass1 blocks / segments
#define SEGCAP 4096u        // mean 3476, sigma 59 -> +10.5 sigma
#define SUPCAP 8192u        // mean 7370, sigma 86 -> +9.5 sigma
#define KSPLIT 4

struct Scalars {
  double sumW;
  double sumW2;
  u64 npruned;
  u64 nflip;
  float stdf;
  float pad;
};

// ---- ws layout (bytes) ----
#define OFF_GHIST  0ull          // 1024 u32
#define OFF_ALLOC  4096ull       // 1024 u32
#define OFF_SBASE  8192ull       // 1024 u32
#define OFF_SCUR   12288ull      // 1024 u32
#define OFF_SC     16384ull      // 128 B
#define OFF_SEGCNT 16512ull      // 2048 u32
#define OFF_XBF    24704ull      // 256*8192*2 = 4,194,304
#define OFF_SEGS   4219008ull    // 2048*4096*4 = 33,554,432
#define OFF_ROUTED 37773440ull   // 8M u32 = 32,000,000
// total ~69.8 MB

// JAX Threefry-2x32, 20 rounds — verified vs known-answer vector
__host__ __device__ inline void tf2x32(u32 k0, u32 k1, u32 x0, u32 x1, u32& y0, u32& y1) {
  u32 ks2 = k0 ^ k1 ^ 0x1BD11BDAu;
  x0 += k0; x1 += k1;
#define TFR(r) { x0 += x1; x1 = (x1 << (r)) | (x1 >> (32 - (r))); x1 ^= x0; }
  TFR(13) TFR(15) TFR(26) TFR(6)  x0 += k1;  x1 += ks2 + 1u;
  TFR(17) TFR(29) TFR(16) TFR(24) x0 += ks2; x1 += k0 + 2u;
  TFR(13) TFR(15) TFR(26) TFR(6)  x0 += k0;  x1 += k1 + 3u;
  TFR(17) TFR(29) TFR(16) TFR(24) x0 += k1;  x1 += ks2 + 4u;
  TFR(13) TFR(15) TFR(26) TFR(6)  x0 += ks2; x1 += k0 + 5u;
#undef TFR
  y0 = x0; y1 = x1;
}

// Partitionable-mode bits for element i: counter (0, i), bits = y0 ^ y1
__device__ inline u32 jax_bits32(u32 k0, u32 k1, u32 i) {
  u32 y0, y1; tf2x32(k0, k1, 0u, i, y0, y1);
  return y0 ^ y1;
}

__device__ inline u16 f2bf(float f) {
  union { float f; u32 u; } c; c.f = f;
  u32 r = ((c.u >> 16) & 1u) + 0x7FFFu;   // RNE
  return (u16)((c.u + r) >> 16);
}

// XLA ErfInv (f32, Giles)
__device__ inline float erfinv32(float x) {
  float w = -log1pf(-x * x);
  float p;
  if (w < 5.0f) {
    w -= 2.5f;
    p = 2.81022636e-08f;
    p = fmaf(p, w, 3.43273939e-07f);
    p = fmaf(p, w, -3.5233877e-06f);
    p = fmaf(p, w, -4.39150654e-06f);
    p = fmaf(p, w, 0.00021858087f);
    p = fmaf(p, w, -0.00125372503f);
    p = fmaf(p, w, -0.00417768164f);
    p = fmaf(p, w, 0.246640727f);
    p = fmaf(p, w, 1.50140941f);
  } else {
    w = sqrtf(w) - 3.0f;
    p = -0.000200214257f;
    p = fmaf(p, w, 0.000100950558f);
    p = fmaf(p, w, 0.00134934322f);
    p = fmaf(p, w, -0.00367342844f);
    p = fmaf(p, w, 0.00573950773f);
    p = fmaf(p, w, -0.0076224613f);
    p = fmaf(p, w, 0.00943887047f);
    p = fmaf(p, w, 1.00167406f);
    p = fmaf(p, w, 2.83297682f);
  }
  return p * x;
}

// ---- block-wide scans over 1024 LDS counters (256 threads) ----
// exclusive ascending prefix: excl[i] = sum_{j<i} cnt[j]
__device__ inline void blk_excl_scan_1024(const u32* cnt, u32* excl, u32* wtmp) {
  __syncthreads();
  u32 t = threadIdx.x;
  u32 a0 = cnt[t*4], a1 = cnt[t*4+1], a2 = cnt[t*4+2], a3 = cnt[t*4+3];
  u32 s = a0 + a1 + a2 + a3;
  u32 lane = t & 63, wv = t >> 6;
  u32 inc = s;
  for (int o = 1; o < 64; o <<= 1) { u32 v = (u32)__shfl_up((int)inc, o); if (lane >= (u32)o) inc += v; }
  if (lane == 63) wtmp[wv] = inc;
  __syncthreads();
  u32 woff = 0;
  for (u32 w = 0; w < wv; w++) woff += wtmp[w];
  u32 base = woff + inc - s;
  excl[t*4]   = base;
  excl[t*4+1] = base + a0;
  excl[t*4+2] = base + a0 + a1;
  excl[t*4+3] = base + a0 + a1 + a2;
  __syncthreads();
}

// exclusive suffix: suf[i] = sum_{j>i} cnt[j]  (scan of reversed stream)
__device__ inline void blk_suffix_scan_1024(const u32* cnt, u32* suf, u32* wtmp) {
  __syncthreads();
  u32 t = threadIdx.x;
  u32 a0 = cnt[1023 - t*4], a1 = cnt[1022 - t*4], a2 = cnt[1021 - t*4], a3 = cnt[1020 - t*4];
  u32 s = a0 + a1 + a2 + a3;
  u32 lane = t & 63, wv = t >> 6;
  u32 inc = s;
  for (int o = 1; o < 64; o <<= 1) { u32 v = (u32)__shfl_up((int)inc, o); if (lane >= (u32)o) inc += v; }
  if (lane == 63) wtmp[wv] = inc;
  __syncthreads();
  u32 woff = 0;
  for (u32 w = 0; w < wv; w++) woff += wtmp[w];
  u32 base = woff + inc - s;
  suf[1023 - t*4] = base;
  suf[1022 - t*4] = base + a0;
  suf[1021 - t*4] = base + a1 + a0;
  suf[1020 - t*4] = base + a2 + a1 + a0;
  __syncthreads();
}

// Pass 1: stream W (float4): f64 sums, prune test, threefry score; candidates
// append u32 idx to PRIVATE per-block segment (wave-ballot, sequential ->
// L2-local, single writeback) + LDS super-histogram. NO random global traffic.
__global__ __launch_bounds__(256) void k_pass1(const float* __restrict__ W, Scalars* sc,
                                               u32* ghist, u32* segcnt, u32* segs,
                                               u32 uk0, u32 uk1) {
  __shared__ u32 lhist[1024];
  __shared__ u32 lcnt, lwr;
  for (u32 j = threadIdx.x; j < 1024; j += 256) lhist[j] = 0;
  if (threadIdx.x == 0) { lcnt = 0; lwr = 0; }
  __syncthreads();
  u32 gid = blockIdx.x * 256 + threadIdx.x;
  u32 stride4 = SEGN * 256 * 4;
  u32 lane = threadIdx.x & 63;
  u64 lt = (lane == 0) ? 0ull : (~0ull >> (64 - lane));
  u32* seg = segs + (u64)blockIdx.x * SEGCAP;
  double s = 0.0, s2 = 0.0; u32 cnt = 0;
  for (u32 b4 = gid * 4; b4 < NTOT; b4 += stride4) {
    float4 wv4 = *(const float4*)(W + b4);
    float we[4] = {wv4.x, wv4.y, wv4.z, wv4.w};
#pragma unroll
    for (int e = 0; e < 4; e++) {
      u32 l = b4 + e;
      float w = we[e];
      s  += (double)w;
      s2 += (double)w * w;
      bool pr = (w == 0.0f);
      cnt += pr ? 1u : 0u;
      u32 sb = jax_bits32(uk0, uk1, l) >> 9;
      bool q = pr && (sb >= T0P);
      u64 m = __ballot(q);
      u32 tot = (u32)__popcll(m);
      if (tot) {
        u32 base = 0;
        if (lane == 0) base = atomicAdd(&lcnt, tot);
        base = (u32)__shfl((int)base, 0);
        if (base + tot <= SEGCAP) {
          if (lane == 0) atomicMax(&lwr, base + tot);
          if (q) {
            seg[base + (u32)__popcll(m & lt)] = l;
            atomicAdd(&lhist[(sb >> 10) - PBASE], 1u);
          }
        }
      }
    }
  }
  for (int o = 32; o > 0; o >>= 1) {
    s += __shfl_down(s, o); s2 += __shfl_down(s2, o); cnt += __shfl_down(cnt, o);
  }
  if (lane == 0) {
    atomicAdd(&sc->sumW, s);
    atomicAdd(&sc->sumW2, s2);
    atomicAdd(&sc->npruned, (u64)cnt);
  }
  __syncthreads();
  for (u32 j = threadIdx.x; j < 1024; j += 256)
    if (j < NSUP && lhist[j]) atomicAdd(&ghist[j], lhist[j]);   // coalesced merge
  if (threadIdx.x == 0) segcnt[blockIdx.x] = lwr;
}

// Scalars + super scans: alloc = ascending-exclusive prefix (layout offsets),
// superbase = suffix-exclusive (global rank base), supercur = alloc copy.
__global__ __launch_bounds__(256) void k_scan(const u32* __restrict__ ghist, Scalars* sc,
                                              u32* alloc, u32* superbase, u32* supercur) {
  __shared__ u32 h[1024], ex[1024], sb[1024], wtmp[4];
  u32 t = threadIdx.x;
  for (u32 j = t; j < 1024; j += 256) h[j] = ghist[j];
  blk_excl_scan_1024(h, ex, wtmp);
  blk_suffix_scan_1024(h, sb, wtmp);
  for (u32 j = t; j < 1024; j += 256) {
    alloc[j] = ex[j]; superbase[j] = sb[j]; supercur[j] = ex[j];
  }
  if (t == 0) {
    double nk = (double)NTOT - (double)sc->npruned;
    double mean = sc->sumW / nk;
    double var = (sc->sumW2 - 2.0 * mean * sc->sumW + nk * mean * mean) / (nk - 1.0);
    sc->stdf = (float)sqrt(var);
    u64 nfi = (u64)(0.1 * (double)sc->npruned);
    if (nfi < 1) nfi = 1;
    sc->nflip = nfi;
  }
}

// Route: 512 blocks x 4 segments (<=16K items): recompute threefry -> super,
// LDS counting-sort by super, reserve contiguous runs (coalesced strided
// atomics), write super-grouped idx array in ~14-item coalesced runs.
__global__ __launch_bounds__(256) void k_route(const u32* __restrict__ segs,
                                               const u32* __restrict__ segcnt,
                                               u32* supercur, u32* routed,
                                               u32 uk0, u32 uk1) {
  __shared__ u32 lbuf[16384];
  __shared__ u16 lp[16384];
  __shared__ u16 inv[16384];
  __shared__ u32 lhist[1024], lbase[1024], gdest[1024], lcur[1024];
  __shared__ u32 wtmp[4];
  u32 t = threadIdx.x;
  for (u32 j = t; j < 1024; j += 256) lhist[j] = 0;
  u32 c0 = segcnt[blockIdx.x*4+0], c1 = segcnt[blockIdx.x*4+1];
  u32 c2 = segcnt[blockIdx.x*4+2], c3 = segcnt[blockIdx.x*4+3];
  u32 off[4] = {0, c0, c0+c1, c0+c1+c2};
  u32 cs[4] = {c0, c1, c2, c3};
  u32 total = c0+c1+c2+c3;
  __syncthreads();
#pragma unroll
  for (int sg = 0; sg < 4; sg++) {
    const u32* sp = segs + ((u64)blockIdx.x*4 + sg) * SEGCAP;
    for (u32 i = t; i < cs[sg]; i += 256) {
      u32 idx = sp[i];
      u32 sb2 = jax_bits32(uk0, uk1, idx) >> 9;
      u32 p = (sb2 >> 10) - PBASE;
      u32 j = off[sg] + i;
      lbuf[j] = idx;
      lp[j] = (u16)p;
      atomicAdd(&lhist[p], 1u);
    }
  }
  blk_excl_scan_1024(lhist, lbase, wtmp);
  for (u32 p = t; p < 1024; p += 256) {
    u32 c = lhist[p];
    if (c) gdest[p] = atomicAdd(&supercur[p], c);
    lcur[p] = lbase[p];
  }
  __syncthreads();
  for (u32 j = t; j < total; j += 256) {
    u32 slot = atomicAdd(&lcur[lp[j]], 1u);
    inv[slot] = (u16)j;
  }
  __syncthreads();
  for (u32 j = t; j < total; j += 256) {
    u32 i = inv[j];
    u32 p = lp[i];
    routed[gdest[p] + (j - lbase[p])] = lbuf[i];    // coalesced runs
  }
}

// Rank: one block per super. Load members (coalesced), recompute fine bin,
// LDS fine-hist + suffix scan + per-fine idx-ordinal -> exact global rank;
// rank < n_flip: threefry val -> W[idx] (the only random scatter left).
__global__ __launch_bounds__(256) void k_rank(float* __restrict__ W,
                                              const u32* __restrict__ ghist,
                                              const u32* __restrict__ alloc,
                                              const u32* __restrict__ superbase,
                                              const u32* __restrict__ routed,
                                              const Scalars* __restrict__ sc,
                                              u32 uk0, u32 uk1, u32 vk0, u32 vk1) {
  u32 p = blockIdx.x;
  u32 n = ghist[p]; if (n == 0) return;
  if (n > SUPCAP) n = SUPCAP;
  u64 nflip = sc->nflip;
  u32 rbase = superbase[p];
  if ((u64)rbase >= nflip) return;
  __shared__ u32 sIdx[SUPCAP];
  __shared__ u16 sFine[SUPCAP];
  __shared__ u32 pIdx[SUPCAP];
  __shared__ u32 hist[1024], gbase[1024], cur[1024];
  __shared__ u32 wtmp[4];
  u32 t = threadIdx.x;
  for (u32 j = t; j < 1024; j += 256) hist[j] = 0;
  __syncthreads();
  const u32* src = routed + alloc[p];
  u32 fbias = (p + PBASE) << 10;
  for (u32 i = t; i < n; i += 256) {
    u32 idx = src[i];
    u32 sb2 = jax_bits32(uk0, uk1, idx) >> 9;
    u32 f = sb2 - fbias;
    sIdx[i] = idx;
    sFine[i] = (u16)f;
    atomicAdd(&hist[f], 1u);
  }
  blk_suffix_scan_1024(hist, gbase, wtmp);   // gbase[f] = # members with fine > f
  for (u32 j = t; j < 1024; j += 256) cur[j] = gbase[j];
  __syncthreads();
  for (u32 i = t; i < n; i += 256) {
    u32 pos = atomicAdd(&cur[sFine[i]], 1u);
    pIdx[pos] = sIdx[i];
  }
  __syncthreads();
  float stdf = sc->stdf;
  for (u32 i = t; i < n; i += 256) {
    u32 f = sFine[i];
    u32 g0 = gbase[f], g1 = g0 + hist[f];
    u32 v = sIdx[i];
    u32 ord = 0;
    for (u32 q = g0; q < g1; q++) ord += (pIdx[q] < v) ? 1u : 0u;
    u64 rank = (u64)rbase + gbase[f] + ord;
    if (rank >= nflip) continue;
    u32 bits = jax_bits32(vk0, vk1, (u32)rank);
    union { u32 u; float fl; } cv; cv.u = 0x3F800000u | (bits >> 9);
    float fu = cv.fl - 1.0f;               // uniform [0,1)
    const float lo = -0.99999994f;         // nextafter(-1,0); (1-lo) rounds to 2.0f
    float u2 = fmaxf(lo, fu * 2.0f + lo);  // uniform [lo, 1)
    float nrm = 1.41421354f * erfinv32(u2);
    W[v] = (nrm * stdf) * 0.1f;
  }
}

// x fp32 -> bf16 once
__global__ __launch_bounds__(256) void k_xconv(const float* __restrict__ x, u16* __restrict__ xbf) {
  u32 i = blockIdx.x * blockDim.x + threadIdx.x;
  float4 v = ((const float4*)x)[i];
  ushort4 o; o.x = f2bf(v.x); o.y = f2bf(v.y); o.z = f2bf(v.z); o.w = f2bf(v.w);
  ((ushort4*)xbf)[i] = o;
}

// GEMM: out[m][n] = sum_k x[m][k] * W[n][k]. M=256 full per block, N tile 64, split-K=4.
typedef __bf16 bf16x8 __attribute__((ext_vector_type(8)));
typedef float f32x4 __attribute__((ext_vector_type(4)));

__global__ __launch_bounds__(256, 2) void k_gemm(const u16* __restrict__ xbf,
                                                 const float* __restrict__ W,
                                                 float* __restrict__ out) {
  __shared__ u16 xs[256 * 72];
  __shared__ u16 wsm[64 * 72];
  u32 tid = threadIdx.x;
  u32 lane = tid & 63, wv = tid >> 6;
  u32 nt0 = blockIdx.x * 64;
  u32 kbase = blockIdx.y * (8192 / KSPLIT);
  f32x4 acc[4][4];
#pragma unroll
  for (int i = 0; i < 4; i++)
#pragma unroll
    for (int j = 0; j < 4; j++) acc[i][j] = (f32x4){0.f, 0.f, 0.f, 0.f};

  for (u32 kb = kbase; kb < kbase + 2048u; kb += 64u) {
#pragma unroll
    for (int r8 = 0; r8 < 8; r8++) {
      u32 row = r8 * 32 + (tid >> 3);
      u32 kseg = (tid & 7) * 8;
      uint4 v = *(const uint4*)(xbf + (u64)row * 8192 + kb + kseg);
      *(uint4*)&xs[row * 72 + kseg] = v;
    }
#pragma unroll
    for (int r = 0; r < 4; r++) {
      u32 f4 = r * 256 + tid;
      u32 row = f4 >> 4;
      u32 kc = (f4 & 15) * 4;
      float4 v = *(const float4*)(W + (u64)(nt0 + row) * 8192 + kb + kc);
      ushort4 o; o.x = f2bf(v.x); o.y = f2bf(v.y); o.z = f2bf(v.z); o.w = f2bf(v.w);
      *(ushort4*)&wsm[row * 72 + kc] = o;
    }
    __syncthreads();
#pragma unroll
    for (int ks = 0; ks < 2; ks++) {
      bf16x8 a[4], b[4];
      u32 koff = ks * 32 + (lane >> 4) * 8;
      u32 rsel = lane & 15;
#pragma unroll
      for (int mt = 0; mt < 4; mt++) a[mt] = *(bf16x8*)&xs[(wv * 64 + mt * 16 + rsel) * 72 + koff];
#pragma unroll
      for (int nt = 0; nt < 4; nt++) b[nt] = *(bf16x8*)&wsm[(nt * 16 + rsel) * 72 + koff];
#pragma unroll
      for (int mt = 0; mt < 4; mt++)
#pragma unroll
        for (int nt = 0; nt < 4; nt++)
          acc[mt][nt] = __builtin_amdgcn_mfma_f32_16x16x32_bf16(a[mt], b[nt], acc[mt][nt], 0, 0, 0);
    }
    __syncthreads();
  }
  u32 quad = lane >> 4, col = lane & 15;
#pragma unroll
  for (int mt = 0; mt < 4; mt++)
#pragma unroll
    for (int nt = 0; nt < 4; nt++) {
      u32 n = nt0 + nt * 16 + col;
#pragma unroll
      for (int rg = 0; rg < 4; rg++) {
        u32 m = wv * 64 + mt * 16 + quad * 4 + rg;
        atomicAdd(&out[(u64)m * 8192 + n], acc[mt][nt][rg]);
      }
    }
}

extern "C" void kernel_launch(void* const* d_in, const int* in_sizes, int n_in,
                              void* d_out, int out_size, void* d_ws, size_t ws_size,
                              hipStream_t stream) {
  const float* x; float* W;
  if (in_sizes[0] == 2097152) { x = (const float*)d_in[0]; W = (float*)d_in[1]; }
  else                        { x = (const float*)d_in[1]; W = (float*)d_in[0]; }
  float* out = (float*)d_out;
  char* ws = (char*)d_ws;

  u32* ghist     = (u32*)(ws + OFF_GHIST);
  u32* alloc     = (u32*)(ws + OFF_ALLOC);
  u32* superbase = (u32*)(ws + OFF_SBASE);
  u32* supercur  = (u32*)(ws + OFF_SCUR);
  Scalars* sc    = (Scalars*)(ws + OFF_SC);
  u32* segcnt    = (u32*)(ws + OFF_SEGCNT);
  u16* xbf       = (u16*)(ws + OFF_XBF);
  u32* segs      = (u32*)(ws + OFF_SEGS);
  u32* routed    = (u32*)(ws + OFF_ROUTED);

  // PARTITIONABLE split of key(42): key[i] = threefry(k=(0,42), counter=(0,i))
  u32 a0, a1, b0, b1;
  tf2x32(0u, 42u, 0u, 0u, a0, a1);   // ks -> uniform scores
  tf2x32(0u, 42u, 0u, 1u, b0, b1);   // kv -> normal vals

  hipMemsetAsync(ghist, 0, 4096, stream);
  hipMemsetAsync(sc, 0, sizeof(Scalars), stream);
  hipMemsetAsync(out, 0, (size_t)out_size * 4, stream);

  k_xconv<<<2048, 256, 0, stream>>>(x, xbf);
  k_pass1<<<SEGN, 256, 0, stream>>>(W, sc, ghist, segcnt, segs, a0, a1);
  k_scan<<<1, 256, 0, stream>>>(ghist, sc, alloc, superbase, supercur);
  k_route<<<SEGN / 4, 256, 0, stream>>>(segs, segcnt, supercur, routed, a0, a1);
  k_rank<<<NSUP, 256, 0, stream>>>(W, ghist, alloc, superbase, routed, sc, a0, a1, b0, b1);
  dim3 g(128, KSPLIT);
  k_gemm<<<g, 256, 0, stream>>>(xbf, W, out);
}

// Round 5
// 1021.959 us; speedup vs baseline: 2.0303x; 1.1285x over previous
//
#include <hip/hip_runtime.h>

typedef unsigned int u32;
typedef unsigned long long u64;
typedef unsigned short u16;

#define NTOT   67108864u    // 8192*8192 = 2^26
#define T0P    7399424u     // candidate threshold = 1932*512*... (PBASE*512); true cutoff ~7.5497M
#define PBASE  14452u       // T0P >> 9
#define NSUP   1932u        // supers of 512 fine bins each, covering [T0P, 2^23)
#define NWSEG  4096u        // per-wave segments (1024 blocks x 4 waves)
#define WCAP   2176u        // per-wave cap: mean 1739, sigma 39.4 -> +11.1 sigma
#define RCAP   4352u        // per-super cap: mean 3686, sigma 60.5 -> +11 sigma
#define KSPLIT 4

struct Scalars {
  double sumW;
  double sumW2;
  u64 npruned;
  u64 nflip;
  float stdf;
  float pad;
};

// ---- ws layout (bytes) ----
#define OFF_COLSUM 0ull          // 2048 u32
#define OFF_ALLOC  8192ull       // 2048 u32
#define OFF_SBASE  16384ull      // 2048 u32
#define OFF_SC     24576ull      // 128 B
#define OFF_SEGCNT 24704ull      // 4096 u32
#define OFF_BHIST  41216ull      // 256*2048*4 = 2,097,152
#define OFF_BDEST  2138368ull    // 2,097,152
#define OFF_XBF    4235520ull    // 256*8192*2 = 4,194,304
#define OFF_SEGS   8429824ull    // 4096*2176*4 = 35,651,584
#define OFF_ROUTED 44081408ull   // 35,651,584
// total ~79.7 MB

// JAX Threefry-2x32, 20 rounds — verified vs known-answer vector
__host__ __device__ inline void tf2x32(u32 k0, u32 k1, u32 x0, u32 x1, u32& y0, u32& y1) {
  u32 ks2 = k0 ^ k1 ^ 0x1BD11BDAu;
  x0 += k0; x1 += k1;
#define TFR(r) { x0 += x1; x1 = (x1 << (r)) | (x1 >> (32 - (r))); x1 ^= x0; }
  TFR(13) TFR(15) TFR(26) TFR(6)  x0 += k1;  x1 += ks2 + 1u;
  TFR(17) TFR(29) TFR(16) TFR(24) x0 += ks2; x1 += k0 + 2u;
  TFR(13) TFR(15) TFR(26) TFR(6)  x0 += k0;  x1 += k1 + 3u;
  TFR(17) TFR(29) TFR(16) TFR(24) x0 += k1;  x1 += ks2 + 4u;
  TFR(13) TFR(15) TFR(26) TFR(6)  x0 += ks2; x1 += k0 + 5u;
#undef TFR
  y0 = x0; y1 = x1;
}

// Partitionable-mode bits for element i: counter (0, i), bits = y0 ^ y1
__device__ inline u32 jax_bits32(u32 k0, u32 k1, u32 i) {
  u32 y0, y1; tf2x32(k0, k1, 0u, i, y0, y1);
  return y0 ^ y1;
}

__device__ inline u16 f2bf(float f) {
  union { float f; u32 u; } c; c.f = f;
  u32 r = ((c.u >> 16) & 1u) + 0x7FFFu;   // RNE
  return (u16)((c.u + r) >> 16);
}

// XLA ErfInv (f32, Giles)
__device__ inline float erfinv32(float x) {
  float w = -log1pf(-x * x);
  float p;
  if (w < 5.0f) {
    w -= 2.5f;
    p = 2.81022636e-08f;
    p = fmaf(p, w, 3.43273939e-07f);
    p = fmaf(p, w, -3.5233877e-06f);
    p = fmaf(p, w, -4.39150654e-06f);
    p = fmaf(p, w, 0.00021858087f);
    p = fmaf(p, w, -0.00125372503f);
    p = fmaf(p, w, -0.00417768164f);
    p = fmaf(p, w, 0.246640727f);
    p = fmaf(p, w, 1.50140941f);
  } else {
    w = sqrtf(w) - 3.0f;
    p = -0.000200214257f;
    p = fmaf(p, w, 0.000100950558f);
    p = fmaf(p, w, 0.00134934322f);
    p = fmaf(p, w, -0.00367342844f);
    p = fmaf(p, w, 0.00573950773f);
    p = fmaf(p, w, -0.0076224613f);
    p = fmaf(p, w, 0.00943887047f);
    p = fmaf(p, w, 1.00167406f);
    p = fmaf(p, w, 2.83297682f);
  }
  return p * x;
}

// Pass 1: stream W (float4); f64 sums; 4 independent threefry chains (ILP);
// candidate append to PRIVATE per-wave segment with REGISTER cursor:
// register prefix-scan + store. No LDS atomics, no shfl-broadcast chains,
// no global histogram. Only traffic: W read + ~29 MB sequential writes.
__global__ __launch_bounds__(256) void k_pass1(const float* __restrict__ W, Scalars* sc,
                                               u32* segcnt, u32* segs, u32 uk0, u32 uk1) {
  u32 t = threadIdx.x;
  u32 gid = blockIdx.x * 256 + t;
  u32 lane = t & 63;
  u32 wid = gid >> 6;
  u32* wseg = segs + (u64)wid * WCAP;
  u32 wbase = 0;                     // wave-uniform cursor, kept in registers
  double s = 0.0, s2 = 0.0; u32 cnt = 0;
  const u32 stride4 = 1024u * 256u * 4u;
  for (u32 b4 = gid * 4; b4 < NTOT; b4 += stride4) {
    float4 w4 = *(const float4*)(W + b4);
    u32 sb0 = jax_bits32(uk0, uk1, b4 + 0) >> 9;   // 4 independent chains
    u32 sb1 = jax_bits32(uk0, uk1, b4 + 1) >> 9;
    u32 sb2 = jax_bits32(uk0, uk1, b4 + 2) >> 9;
    u32 sb3 = jax_bits32(uk0, uk1, b4 + 3) >> 9;
    float we[4] = {w4.x, w4.y, w4.z, w4.w};
    u32 sbv[4] = {sb0, sb1, sb2, sb3};
    u32 cand[4]; u32 nc = 0;
#pragma unroll
    for (int e = 0; e < 4; e++) {
      float w = we[e];
      s  += (double)w;
      s2 += (double)w * (double)w;
      bool pr = (w == 0.0f);
      cnt += pr ? 1u : 0u;
      if (pr && sbv[e] >= T0P) { cand[nc] = b4 + e; nc++; }
    }
    u32 inc = nc;                    // wave inclusive scan of per-lane counts
#pragma unroll
    for (int o = 1; o < 64; o <<= 1) { u32 v = (u32)__shfl_up((int)inc, o); if (lane >= (u32)o) inc += v; }
    u32 tot = (u32)__shfl((int)inc, 63);
    u32 pos = wbase + inc - nc;
    for (u32 k2 = 0; k2 < nc; k2++)
      if (pos + k2 < WCAP) wseg[pos + k2] = cand[k2];
    wbase += tot;
  }
  for (int o = 32; o > 0; o >>= 1) {
    s += __shfl_down(s, o); s2 += __shfl_down(s2, o); cnt += __shfl_down(cnt, o);
  }
  if (lane == 0) {
    atomicAdd(&sc->sumW, s);
    atomicAdd(&sc->sumW2, s2);
    atomicAdd(&sc->npruned, (u64)cnt);
    segcnt[wid] = (wbase > WCAP) ? WCAP : wbase;
  }
}

// Route A: per-block super-histogram (LDS only) -> bhist[block][2048] row.
__global__ __launch_bounds__(256) void k_route_a(const u32* __restrict__ segs,
                                                 const u32* __restrict__ segcnt,
                                                 u32* bhist, u32 uk0, u32 uk1) {
  __shared__ u32 lhist[2048];
  u32 t = threadIdx.x;
  for (u32 j = t; j < 2048; j += 256) lhist[j] = 0;
  __syncthreads();
#pragma unroll 1
  for (int sg = 0; sg < 16; sg++) {
    u32 wid = blockIdx.x * 16 + sg;
    u32 n = segcnt[wid]; if (n > WCAP) n = WCAP;
    const u32* sp = segs + (u64)wid * WCAP;
    for (u32 i = t; i < n; i += 256) {
      u32 sup = (jax_bits32(uk0, uk1, sp[i]) >> 18) - PBASE;
      atomicAdd(&lhist[sup], 1u);
    }
  }
  __syncthreads();
  for (u32 j = t; j < 2048; j += 256) bhist[blockIdx.x * 2048 + j] = lhist[j];
}

// Column scan: per super s, exclusive prefix of bhist[b][s] over blocks b
// (deterministic replacement for contended reserve-atomics) + column totals.
__global__ __launch_bounds__(256) void k_colscan(const u32* __restrict__ bhist,
                                                 u32* bdest, u32* colsum) {
  __shared__ u32 wtmp[4];
  u32 s = blockIdx.x, t = threadIdx.x, lane = t & 63, wv = t >> 6;
  u32 v = bhist[t * 2048 + s];
  u32 inc = v;
#pragma unroll
  for (int o = 1; o < 64; o <<= 1) { u32 x = (u32)__shfl_up((int)inc, o); if (lane >= (u32)o) inc += x; }
  if (lane == 63) wtmp[wv] = inc;
  __syncthreads();
  u32 woff = 0;
  for (u32 w = 0; w < wv; w++) woff += wtmp[w];
  bdest[t * 2048 + s] = woff + inc - v;
  if (t == 255) colsum[s] = woff + inc;
}

// Scalars + 2048-wide prefix (alloc = routed layout) & suffix (sbase = rank base).
__global__ __launch_bounds__(256) void k_scan(const u32* __restrict__ colsum, Scalars* sc,
                                              u32* alloc, u32* sbase) {
  __shared__ u32 h[2048];
  __shared__ u32 wtmp[4];
  u32 t = threadIdx.x, lane = t & 63, wv = t >> 6;
  for (u32 j = t; j < 2048; j += 256) h[j] = colsum[j];
  __syncthreads();
  {
    u32 a[8]; u32 s8 = 0;
#pragma unroll
    for (int k = 0; k < 8; k++) { a[k] = h[t * 8 + k]; s8 += a[k]; }
    u32 inc = s8;
#pragma unroll
    for (int o = 1; o < 64; o <<= 1) { u32 v = (u32)__shfl_up((int)inc, o); if (lane >= (u32)o) inc += v; }
    if (lane == 63) wtmp[wv] = inc;
    __syncthreads();
    u32 woff = 0; for (u32 w = 0; w < wv; w++) woff += wtmp[w];
    u32 base = woff + inc - s8;
#pragma unroll
    for (int k = 0; k < 8; k++) { alloc[t * 8 + k] = base; base += a[k]; }
    __syncthreads();
  }
  {
    u32 a[8]; u32 s8 = 0;
#pragma unroll
    for (int k = 0; k < 8; k++) { a[k] = h[2047 - (t * 8 + k)]; s8 += a[k]; }
    u32 inc = s8;
#pragma unroll
    for (int o = 1; o < 64; o <<= 1) { u32 v = (u32)__shfl_up((int)inc, o); if (lane >= (u32)o) inc += v; }
    if (lane == 63) wtmp[wv] = inc;
    __syncthreads();
    u32 woff = 0; for (u32 w = 0; w < wv; w++) woff += wtmp[w];
    u32 base = woff + inc - s8;
#pragma unroll
    for (int k = 0; k < 8; k++) { sbase[2047 - (t * 8 + k)] = base; base += a[k]; }
  }
  if (t == 0) {
    double nk = (double)NTOT - (double)sc->npruned;
    double mean = sc->sumW / nk;
    double var = (sc->sumW2 - 2.0 * mean * sc->sumW + nk * mean * mean) / (nk - 1.0);
    sc->stdf = (float)sqrt(var);
    u64 nfi = (u64)(0.1 * (double)sc->npruned);
    if (nfi < 1) nfi = 1;
    sc->nflip = nfi;
  }
}

// Route B: re-stream segments; LDS cursors pre-seeded from alloc+bdest
// (deterministic slots, no global atomics); write super-grouped routed.
__global__ __launch_bounds__(256) void k_route_b(const u32* __restrict__ segs,
                                                 const u32* __restrict__ segcnt,
                                                 const u32* __restrict__ alloc,
                                                 const u32* __restrict__ bdest,
                                                 u32* routed, u32 uk0, u32 uk1) {
  __shared__ u32 lcur[2048];
  u32 t = threadIdx.x;
  for (u32 j = t; j < 2048; j += 256) lcur[j] = alloc[j] + bdest[blockIdx.x * 2048 + j];
  __syncthreads();
#pragma unroll 1
  for (int sg = 0; sg < 16; sg++) {
    u32 wid = blockIdx.x * 16 + sg;
    u32 n = segcnt[wid]; if (n > WCAP) n = WCAP;
    const u32* sp = segs + (u64)wid * WCAP;
    for (u32 i = t; i < n; i += 256) {
      u32 idx = sp[i];
      u32 sup = (jax_bits32(uk0, uk1, idx) >> 18) - PBASE;
      u32 pos = atomicAdd(&lcur[sup], 1u);
      routed[pos] = idx;
    }
  }
}

// 512-bin suffix-exclusive scan (256 threads, 2 bins each)
__device__ inline void suf512(const u32* cnt, u32* suf, u32* wtmp) {
  u32 t = threadIdx.x, lane = t & 63, wv = t >> 6;
  u32 a0 = cnt[511 - t * 2], a1 = cnt[510 - t * 2];
  u32 s = a0 + a1;
  u32 inc = s;
#pragma unroll
  for (int o = 1; o < 64; o <<= 1) { u32 v = (u32)__shfl_up((int)inc, o); if (lane >= (u32)o) inc += v; }
  if (lane == 63) wtmp[wv] = inc;
  __syncthreads();
  u32 woff = 0;
  for (u32 w = 0; w < wv; w++) woff += wtmp[w];
  u32 base = woff + inc - s;
  suf[511 - t * 2] = base;
  suf[510 - t * 2] = base + a0;
  __syncthreads();
}

// Rank: one block per 512-bin super (~50 KB LDS -> 3 blocks/CU). Fine-hist,
// suffix scan, stable ascending-idx ordinal -> exact global rank; winners:
// threefry val -> W[idx] (the only random scatter in the pipeline).
__global__ __launch_bounds__(256) void k_rank(float* __restrict__ W,
                                              const u32* __restrict__ colsum,
                                              const u32* __restrict__ alloc,
                                              const u32* __restrict__ sbase,
                                              const u32* __restrict__ routed,
                                              const Scalars* __restrict__ sc,
                                              u32 uk0, u32 uk1, u32 vk0, u32 vk1) {
  u32 p = blockIdx.x;
  u32 n = colsum[p]; if (n == 0) return;
  if (n > RCAP) n = RCAP;
  u64 nflip = sc->nflip;
  u32 rbase = sbase[p];
  if ((u64)rbase >= nflip) return;
  __shared__ u32 sIdx[RCAP];
  __shared__ u16 sFine[RCAP];
  __shared__ u32 pIdx[RCAP];
  __shared__ u32 hist[512], gbase[512], cur[512], wtmp[4];
  u32 t = threadIdx.x;
  for (u32 j = t; j < 512; j += 256) hist[j] = 0;
  __syncthreads();
  const u32* src = routed + alloc[p];
  for (u32 i = t; i < n; i += 256) {
    u32 idx = src[i];
    u32 f = (jax_bits32(uk0, uk1, idx) >> 9) & 511u;
    sIdx[i] = idx;
    sFine[i] = (u16)f;
    atomicAdd(&hist[f], 1u);
  }
  __syncthreads();
  suf512(hist, gbase, wtmp);         // gbase[f] = # members with fine > f
  for (u32 j = t; j < 512; j += 256) cur[j] = gbase[j];
  __syncthreads();
  for (u32 i = t; i < n; i += 256) {
    u32 pos = atomicAdd(&cur[sFine[i]], 1u);
    pIdx[pos] = sIdx[i];
  }
  __syncthreads();
  float stdf = sc->stdf;
  for (u32 i = t; i < n; i += 256) {
    u32 f = sFine[i];
    u32 g0 = gbase[f], g1 = g0 + hist[f];
    u32 v = sIdx[i];
    u32 ord = 0;
    for (u32 q = g0; q < g1; q++) ord += (pIdx[q] < v) ? 1u : 0u;
    u64 rank = (u64)rbase + g0 + ord;
    if (rank >= nflip) continue;
    u32 bits = jax_bits32(vk0, vk1, (u32)rank);
    union { u32 u; float fl; } cv; cv.u = 0x3F800000u | (bits >> 9);
    float fu = cv.fl - 1.0f;               // uniform [0,1)
    const float lo = -0.99999994f;         // nextafter(-1,0); (1-lo) rounds to 2.0f
    float u2 = fmaxf(lo, fu * 2.0f + lo);  // uniform [lo, 1)
    float nrm = 1.41421354f * erfinv32(u2);
    W[v] = (nrm * stdf) * 0.1f;
  }
}

// x fp32 -> bf16 once
__global__ __launch_bounds__(256) void k_xconv(const float* __restrict__ x, u16* __restrict__ xbf) {
  u32 i = blockIdx.x * blockDim.x + threadIdx.x;
  float4 v = ((const float4*)x)[i];
  ushort4 o; o.x = f2bf(v.x); o.y = f2bf(v.y); o.z = f2bf(v.z); o.w = f2bf(v.w);
  ((ushort4*)xbf)[i] = o;
}

// GEMM: out[m][n] = sum_k x[m][k] * W[n][k]. M=256 full per block, N tile 64, split-K=4.
typedef __bf16 bf16x8 __attribute__((ext_vector_type(8)));
typedef float f32x4 __attribute__((ext_vector_type(4)));

__global__ __launch_bounds__(256, 2) void k_gemm(const u16* __restrict__ xbf,
                                                 const float* __restrict__ W,
                                                 float* __restrict__ out) {
  __shared__ u16 xs[256 * 72];
  __shared__ u16 wsm[64 * 72];
  u32 tid = threadIdx.x;
  u32 lane = tid & 63, wv = tid >> 6;
  u32 nt0 = blockIdx.x * 64;
  u32 kbase = blockIdx.y * (8192 / KSPLIT);
  f32x4 acc[4][4];
#pragma unroll
  for (int i = 0; i < 4; i++)
#pragma unroll
    for (int j = 0; j < 4; j++) acc[i][j] = (f32x4){0.f, 0.f, 0.f, 0.f};

  for (u32 kb = kbase; kb < kbase + 2048u; kb += 64u) {
#pragma unroll
    for (int r8 = 0; r8 < 8; r8++) {
      u32 row = r8 * 32 + (tid >> 3);
      u32 kseg = (tid & 7) * 8;
      uint4 v = *(const uint4*)(xbf + (u64)row * 8192 + kb + kseg);
      *(uint4*)&xs[row * 72 + kseg] = v;
    }
#pragma unroll
    for (int r = 0; r < 4; r++) {
      u32 f4 = r * 256 + tid;
      u32 row = f4 >> 4;
      u32 kc = (f4 & 15) * 4;
      float4 v = *(const float4*)(W + (u64)(nt0 + row) * 8192 + kb + kc);
      ushort4 o; o.x = f2bf(v.x); o.y = f2bf(v.y); o.z = f2bf(v.z); o.w = f2bf(v.w);
      *(ushort4*)&wsm[row * 72 + kc] = o;
    }
    __syncthreads();
#pragma unroll
    for (int ks = 0; ks < 2; ks++) {
      bf16x8 a[4], b[4];
      u32 koff = ks * 32 + (lane >> 4) * 8;
      u32 rsel = lane & 15;
#pragma unroll
      for (int mt = 0; mt < 4; mt++) a[mt] = *(bf16x8*)&xs[(wv * 64 + mt * 16 + rsel) * 72 + koff];
#pragma unroll
      for (int nt = 0; nt < 4; nt++) b[nt] = *(bf16x8*)&wsm[(nt * 16 + rsel) * 72 + koff];
#pragma unroll
      for (int mt = 0; mt < 4; mt++)
#pragma unroll
        for (int nt = 0; nt < 4; nt++)
          acc[mt][nt] = __builtin_amdgcn_mfma_f32_16x16x32_bf16(a[mt], b[nt], acc[mt][nt], 0, 0, 0);
    }
    __syncthreads();
  }
  u32 quad = lane >> 4, col = lane & 15;
#pragma unroll
  for (int mt = 0; mt < 4; mt++)
#pragma unroll
    for (int nt = 0; nt < 4; nt++) {
      u32 n = nt0 + nt * 16 + col;
#pragma unroll
      for (int rg = 0; rg < 4; rg++) {
        u32 m = wv * 64 + mt * 16 + quad * 4 + rg;
        atomicAdd(&out[(u64)m * 8192 + n], acc[mt][nt][rg]);
      }
    }
}

extern "C" void kernel_launch(void* const* d_in, const int* in_sizes, int n_in,
                              void* d_out, int out_size, void* d_ws, size_t ws_size,
                              hipStream_t stream) {
  const float* x; float* W;
  if (in_sizes[0] == 2097152) { x = (const float*)d_in[0]; W = (float*)d_in[1]; }
  else                        { x = (const float*)d_in[1]; W = (float*)d_in[0]; }
  float* out = (float*)d_out;
  char* ws = (char*)d_ws;

  u32* colsum = (u32*)(ws + OFF_COLSUM);
  u32* alloc  = (u32*)(ws + OFF_ALLOC);
  u32* sbase  = (u32*)(ws + OFF_SBASE);
  Scalars* sc = (Scalars*)(ws + OFF_SC);
  u32* segcnt = (u32*)(ws + OFF_SEGCNT);
  u32* bhist  = (u32*)(ws + OFF_BHIST);
  u32* bdest  = (u32*)(ws + OFF_BDEST);
  u16* xbf    = (u16*)(ws + OFF_XBF);
  u32* segs   = (u32*)(ws + OFF_SEGS);
  u32* routed = (u32*)(ws + OFF_ROUTED);

  // PARTITIONABLE split of key(42): key[i] = threefry(k=(0,42), counter=(0,i))
  u32 a0, a1, b0, b1;
  tf2x32(0u, 42u, 0u, 0u, a0, a1);   // ks -> uniform scores
  tf2x32(0u, 42u, 0u, 1u, b0, b1);   // kv -> normal vals

  hipMemsetAsync(sc, 0, sizeof(Scalars), stream);
  hipMemsetAsync(out, 0, (size_t)out_size * 4, stream);

  k_xconv<<<2048, 256, 0, stream>>>(x, xbf);
  k_pass1<<<1024, 256, 0, stream>>>(W, sc, segcnt, segs, a0, a1);
  k_route_a<<<256, 256, 0, stream>>>(segs, segcnt, bhist, a0, a1);
  k_colscan<<<2048, 256, 0, stream>>>(bhist, bdest, colsum);
  k_scan<<<1, 256, 0, stream>>>(colsum, sc, alloc, sbase);
  k_route_b<<<256, 256, 0, stream>>>(segs, segcnt, alloc, bdest, routed, a0, a1);
  k_rank<<<NSUP, 256, 0, stream>>>(W, colsum, alloc, sbase, routed, sc, a0, a1, b0, b1);
  dim3 g(128, KSPLIT);
  k_gemm<<<g, 256, 0, stream>>>(xbf, W, out);
}